// Round 8
// baseline (336.036 us; speedup 1.0000x reference)
//
#include <hip/hip_runtime.h>

typedef unsigned short u16;
typedef unsigned int u32;
typedef __bf16 bf16x8 __attribute__((ext_vector_type(8)));
typedef float f32x16 __attribute__((ext_vector_type(16)));

__device__ __forceinline__ u16 f2bf(float f) {
  u32 u = __builtin_bit_cast(u32, f);
  u = (u + 0x7FFFu + ((u >> 16) & 1u)) >> 16;
  return (u16)u;
}
__device__ __forceinline__ float bf2f(u16 h) {
  u32 u = ((u32)h) << 16;
  return __builtin_bit_cast(float, u);
}

#define GLD16(gp, lp) __builtin_amdgcn_global_load_lds( \
    (const __attribute__((address_space(1))) u32*)(const void*)(gp), \
    (__attribute__((address_space(3))) u32*)(void*)(lp), 16, 0, 0)
#define SBAR() __builtin_amdgcn_s_barrier()
#define SCHED0() __builtin_amdgcn_sched_barrier(0)

// ---------------------------------------------------------------------------
// both weight casts in one launch
__global__ __launch_bounds__(256) void cast_both(const float* __restrict__ w_in,
                                                 u16* __restrict__ wq,
                                                 const float* __restrict__ w_out,
                                                 u16* __restrict__ wo) {
  int i = blockIdx.x * 256 + threadIdx.x;
  const float* src = w_in; u16* dst = wq; int idx = i;
  if (i >= 196608) { src = w_out; dst = wo; idx = i - 196608; }
  float4 v = *(const float4*)(src + (size_t)idx * 4);
  ushort4 u;
  u.x = f2bf(v.x); u.y = f2bf(v.y); u.z = f2bf(v.z); u.w = f2bf(v.w);
  *(ushort4*)(dst + (size_t)idx * 4) = u;
}

// ---------------------------------------------------------------------------
// permute_in: x (B,C,64,64,64) fp32 -> xw rows n-major: row = nw*8 + b, col e
__global__ __launch_bounds__(256) void permute_in(const float* __restrict__ x,
                                                  u16* __restrict__ xw) {
  __shared__ float lds[128 * 64];
  int t = threadIdx.x;
  int bx = blockIdx.x;                 // jx*16 + jy
  int b = blockIdx.y;
  int jx = bx >> 4, jy = bx & 15;
#pragma unroll
  for (int it = 0; it < 8; ++it) {
    int idx = t + it * 256;
    int row = idx >> 4, z4 = idx & 15;
    int c = row >> 4, qx = (row >> 2) & 3, qy = row & 3;
    int X = (jx * 4 + qx + 60) & 63;
    int Y = (jy * 4 + qy + 60) & 63;
    float4 v = *(const float4*)(x + ((((size_t)(b * 8 + c) * 64 + X) * 64 + Y) * 64 + z4 * 4));
    *(float4*)(lds + row * 64 + ((z4 ^ (row & 7)) << 2)) = v;
  }
  __syncthreads();
#pragma unroll
  for (int it = 0; it < 8; ++it) {
    int idx = t + it * 256;
    int jz = idx >> 7, r = idx & 127;
    int z4r = (jz + 15) & 15;
    float4 v = *(const float4*)(lds + r * 64 + ((z4r ^ (r & 7)) << 2));
    int nw = jx * 256 + jy * 16 + jz;
    ushort4 u;
    u.x = f2bf(v.x); u.y = f2bf(v.y); u.z = f2bf(v.z); u.w = f2bf(v.w);
    *(ushort4*)(xw + (size_t)(nw * 8 + b) * 512 + r * 4) = u;
  }
}

// ---------------------------------------------------------------------------
// Fused QKV GEMM + attention. Block = 128 rows x 192 cols (Q|K|V of head h),
// 256 threads (4 waves, 2x2), 32x32x16 MFMA, BK=32 double-buffer.
// LDS swizzle uses ROW-PAIR bits: chunkslot = chunk ^ ((row>>1)&3) so a
// fragment ds_read_b128 phase covers all 8 bank-quads (2 lanes/quad = free).
// Attention epilogue uses an fp32 ctile (stride 204) aliased onto the dead
// staging buffers. LDS 40960 B -> 4 blocks/CU.
__global__ __launch_bounds__(256, 4) void gemm_qkv_attn(const u16* __restrict__ A,
                                                        const u16* __restrict__ W,
                                                        const float* __restrict__ bias,
                                                        u16* __restrict__ O) {
  __shared__ u16 smem[20480];  // 40960 B: As[2][4096] + Bs[2][6144]; ctf aliases
  u16* As = smem;
  u16* Bs = smem + 8192;
  float* ctf = (float*)smem;   // [32][204] f32 = 26112 B (epilogue only)

  int cpx = gridDim.x >> 3;    // 2048/8 = 256
  int wg = (blockIdx.x & 7) * cpx + (blockIdx.x >> 3);
  int mbc = wg >> 3, h = wg & 7;
  int m0 = mbc * 128;

  int tid = threadIdx.x;
  int wv = tid >> 6, l = tid & 63;
  int wr = wv >> 1, wc = wv & 1;
  int l31 = l & 31, g = l >> 5;

  // staging: slot s -> row = s>>2, chunkslot = s&3 holds data chunk (s&3)^((s>>3)&3)
  int kch = ((l & 3) ^ ((l >> 3) & 3)) * 8;
  const u16* pa[2]; int dA[2];
#pragma unroll
  for (int i = 0; i < 2; ++i) {
    int slot = wv * 128 + i * 64 + l;
    int row = slot >> 2;                     // 0..127
    pa[i] = A + (size_t)(m0 + row) * 512 + kch;
    dA[i] = (wv * 128 + i * 64) * 8;
  }
  const u16* pb[3]; int dB[3];
#pragma unroll
  for (int i = 0; i < 3; ++i) {
    int slot = wv * 192 + i * 64 + l;
    int row = slot >> 2;                     // 0..191
    int grow = (row >> 6) * 512 + h * 64 + (row & 63);
    pb[i] = W + (size_t)grow * 512 + kch;
    dB[i] = (wv * 192 + i * 64) * 8;
  }

  int abase[2], bbase[3];
#pragma unroll
  for (int m = 0; m < 2; ++m) abase[m] = (wr * 64 + m * 32 + l31) * 32;
#pragma unroll
  for (int n = 0; n < 3; ++n) bbase[n] = (wc * 96 + n * 32 + l31) * 32;
  int rsw = (l31 >> 1) & 3;    // row-pair swizzle bits for fragment reads

  f32x16 acc[2][3] = {};

  // prologue: stage tile 0 -> buf 0
  GLD16(pa[0], As + dA[0]); GLD16(pa[1], As + dA[1]);
  GLD16(pb[0], Bs + dB[0]); GLD16(pb[1], Bs + dB[1]); GLD16(pb[2], Bs + dB[2]);
  asm volatile("s_waitcnt vmcnt(0)" ::: "memory");
  SCHED0(); SBAR(); SCHED0();

  for (int t = 0; t < 16; ++t) {
    const u16* AsT = As + (t & 1) * 4096;
    const u16* BsT = Bs + (t & 1) * 6144;
    u16* Ad = As + ((t + 1) & 1) * 4096;
    u16* Bd = Bs + ((t + 1) & 1) * 6144;
    int nx = (t + 1) * 32;
    bool st = t < 15;
#pragma unroll
    for (int s = 0; s < 2; ++s) {
      int cofs = ((((s << 1) | g) ^ rsw)) << 3;
      bf16x8 af[2], bf[3];
      af[0] = *(const bf16x8*)(AsT + abase[0] + cofs);
      af[1] = *(const bf16x8*)(AsT + abase[1] + cofs);
      bf[0] = *(const bf16x8*)(BsT + bbase[0] + cofs);
      bf[1] = *(const bf16x8*)(BsT + bbase[1] + cofs);
      bf[2] = *(const bf16x8*)(BsT + bbase[2] + cofs);
      if (s == 0 && st) { GLD16(pa[0] + nx, Ad + dA[0]); GLD16(pa[1] + nx, Ad + dA[1]); }
      if (s == 1 && st) {
        GLD16(pb[0] + nx, Bd + dB[0]); GLD16(pb[1] + nx, Bd + dB[1]);
        GLD16(pb[2] + nx, Bd + dB[2]);
      }
      SCHED0();
      __builtin_amdgcn_s_setprio(1);
#pragma unroll
      for (int m = 0; m < 2; ++m)
#pragma unroll
        for (int n = 0; n < 3; ++n)
          acc[m][n] = __builtin_amdgcn_mfma_f32_32x32x16_bf16(bf[n], af[m], acc[m][n], 0, 0, 0);
      __builtin_amdgcn_s_setprio(0);
      SCHED0();
    }
    asm volatile("s_waitcnt vmcnt(0)" ::: "memory");
    SCHED0(); SBAR(); SCHED0();
  }

  // ---- chunked epilogue: 4 chunks of 32 rows; fp32 ctile, no bf16 round-trip
#pragma unroll 1
  for (int c = 0; c < 4; ++c) {
    if ((c >> 1) == wr) {
      int m = c & 1;
#pragma unroll
      for (int n = 0; n < 3; ++n)
#pragma unroll
        for (int q = 0; q < 4; ++q) {
          int col0 = wc * 96 + n * 32 + q * 8 + g * 4;
          int gcol = ((col0 >> 6) << 9) + (h << 6) + (col0 & 63);
          float4 bv = *(const float4*)(bias + gcol);
          float4 stv;
          stv.x = acc[m][n][q * 4 + 0] + bv.x;
          stv.y = acc[m][n][q * 4 + 1] + bv.y;
          stv.z = acc[m][n][q * 4 + 2] + bv.z;
          stv.w = acc[m][n][q * 4 + 3] + bv.w;
          *(float4*)(ctf + l31 * 204 + col0) = stv;
        }
    }
    __syncthreads();
    // attention: wave wv handles window wv of this chunk (8 rows)
    {
      int qi = l >> 3, j = l & 7;
      const float* qr = ctf + (wv * 8 + qi) * 204;
      const float* kr = ctf + (wv * 8 + j) * 204 + 64;
      float sc = 0.f;
#pragma unroll
      for (int d = 0; d < 16; ++d) {
        float4 qv = *(const float4*)(qr + d * 4);
        float4 kv = *(const float4*)(kr + d * 4);
        sc += qv.x * kv.x + qv.y * kv.y + qv.z * kv.z + qv.w * kv.w;
      }
      sc *= 0.125f;
      float mx = sc;
      mx = fmaxf(mx, __shfl_xor(mx, 1));
      mx = fmaxf(mx, __shfl_xor(mx, 2));
      mx = fmaxf(mx, __shfl_xor(mx, 4));
      float p = __expf(sc - mx);
      float sum = p;
      sum += __shfl_xor(sum, 1);
      sum += __shfl_xor(sum, 2);
      sum += __shfl_xor(sum, 4);
      p /= sum;
      float pr[8];
      int lb = l & 56;
#pragma unroll
      for (int jj = 0; jj < 8; ++jj) pr[jj] = __shfl(p, lb + jj);
      float ov[8] = {};
#pragma unroll
      for (int jj = 0; jj < 8; ++jj) {
        const float* vr = ctf + (wv * 8 + jj) * 204 + 128 + j * 8;
        float4 va = *(const float4*)(vr);
        float4 vb = *(const float4*)(vr + 4);
        float pj = pr[jj];
        ov[0] += pj * va.x; ov[1] += pj * va.y; ov[2] += pj * va.z; ov[3] += pj * va.w;
        ov[4] += pj * vb.x; ov[5] += pj * vb.y; ov[6] += pj * vb.z; ov[7] += pj * vb.w;
      }
      ushort4 r0, r1;
      r0.x = f2bf(ov[0]); r0.y = f2bf(ov[1]); r0.z = f2bf(ov[2]); r0.w = f2bf(ov[3]);
      r1.x = f2bf(ov[4]); r1.y = f2bf(ov[5]); r1.z = f2bf(ov[6]); r1.w = f2bf(ov[7]);
      u16* dst = O + (size_t)(m0 + c * 32 + wv * 8 + qi) * 512 + h * 64 + j * 8;
      *(ushort4*)dst = r0;
      *(ushort4*)(dst + 4) = r1;
    }
    __syncthreads();
  }
}

// ---------------------------------------------------------------------------
// out-proj GEMM: C[32768,512] = o @ wo^T + bias. Block 256x128, 512 thr
// (8 waves, 4x2), 32x32x16 MFMA, BK=32, row-pair swizzle, grid 512.
__global__ __launch_bounds__(512, 4) void gemm_out(const u16* __restrict__ A,
                                                   const u16* __restrict__ Wt,
                                                   const float* __restrict__ bias,
                                                   u16* __restrict__ C) {
  __shared__ u16 smem[24576];
  u16* As = smem;            // [2][8192]  (256 rows x 32 k)
  u16* Bs = smem + 16384;    // [2][4096]  (128 rows x 32 k)

  int cpx = gridDim.x >> 3;  // 512/8 = 64
  int wg = (blockIdx.x & 7) * cpx + (blockIdx.x >> 3);
  int mb = wg >> 2, nb = wg & 3;
  int m0 = mb * 256, n0 = nb * 128;

  int tid = threadIdx.x;
  int wv = tid >> 6, l = tid & 63;
  int wr = wv >> 1, wc = wv & 1;
  int l31 = l & 31, g = l >> 5;

  int kch = ((l & 3) ^ ((l >> 3) & 3)) * 8;
  const u16* pa[2]; int dA[2];
#pragma unroll
  for (int i = 0; i < 2; ++i) {
    int slot = wv * 128 + i * 64 + l;
    int row = slot >> 2;                     // 0..255
    pa[i] = A + (size_t)(m0 + row) * 512 + kch;
    dA[i] = (wv * 128 + i * 64) * 8;
  }
  int slotB = wv * 64 + l;
  int rowB = slotB >> 2;                     // 0..127
  const u16* pb = Wt + (size_t)(n0 + rowB) * 512 + kch;
  int dB = (wv * 64) * 8;

  int abase[2], bbase[2];
#pragma unroll
  for (int m = 0; m < 2; ++m) abase[m] = (wr * 64 + m * 32 + l31) * 32;
#pragma unroll
  for (int n = 0; n < 2; ++n) bbase[n] = (wc * 64 + n * 32 + l31) * 32;
  int rsw = (l31 >> 1) & 3;

  f32x16 acc[2][2] = {};

  GLD16(pa[0], As + dA[0]); GLD16(pa[1], As + dA[1]);
  GLD16(pb, Bs + dB);
  asm volatile("s_waitcnt vmcnt(0)" ::: "memory");
  SCHED0(); SBAR(); SCHED0();

  for (int t = 0; t < 16; ++t) {
    const u16* AsT = As + (t & 1) * 8192;
    const u16* BsT = Bs + (t & 1) * 4096;
    u16* Ad = As + ((t + 1) & 1) * 8192;
    u16* Bd = Bs + ((t + 1) & 1) * 4096;
    int nx = (t + 1) * 32;
    bool st = t < 15;
#pragma unroll
    for (int s = 0; s < 2; ++s) {
      int cofs = ((((s << 1) | g) ^ rsw)) << 3;
      bf16x8 af[2], bf[2];
      af[0] = *(const bf16x8*)(AsT + abase[0] + cofs);
      af[1] = *(const bf16x8*)(AsT + abase[1] + cofs);
      bf[0] = *(const bf16x8*)(BsT + bbase[0] + cofs);
      bf[1] = *(const bf16x8*)(BsT + bbase[1] + cofs);
      if (s == 0 && st) { GLD16(pa[0] + nx, Ad + dA[0]); GLD16(pa[1] + nx, Ad + dA[1]); }
      if (s == 1 && st) { GLD16(pb + nx, Bd + dB); }
      SCHED0();
      __builtin_amdgcn_s_setprio(1);
#pragma unroll
      for (int m = 0; m < 2; ++m)
#pragma unroll
        for (int n = 0; n < 2; ++n)
          acc[m][n] = __builtin_amdgcn_mfma_f32_32x32x16_bf16(bf[n], af[m], acc[m][n], 0, 0, 0);
      __builtin_amdgcn_s_setprio(0);
      SCHED0();
    }
    asm volatile("s_waitcnt vmcnt(0)" ::: "memory");
    SCHED0(); SBAR(); SCHED0();
  }

#pragma unroll
  for (int m = 0; m < 2; ++m) {
    size_t row = (size_t)(m0 + wr * 64 + m * 32 + l31);
#pragma unroll
    for (int n = 0; n < 2; ++n)
#pragma unroll
      for (int q = 0; q < 4; ++q) {
        int col0 = n0 + wc * 64 + n * 32 + q * 8 + g * 4;
        float4 bv = *(const float4*)(bias + col0);
        ushort4 uu;
        uu.x = f2bf(acc[m][n][q * 4 + 0] + bv.x);
        uu.y = f2bf(acc[m][n][q * 4 + 1] + bv.y);
        uu.z = f2bf(acc[m][n][q * 4 + 2] + bv.z);
        uu.w = f2bf(acc[m][n][q * 4 + 3] + bv.w);
        *(ushort4*)(C + row * 512 + col0) = uu;
      }
  }
}

// ---------------------------------------------------------------------------
// permute_out: o2 rows n-major (row = n*8+b) bf16 -> out (B,C,64,64,64) fp32
__global__ __launch_bounds__(256) void permute_out(const u16* __restrict__ o2,
                                                   float* __restrict__ out) {
  __shared__ float lds[16 * 516];
  int t = threadIdx.x;
  int bx = blockIdx.x;
  int b = blockIdx.y;
  int ix = bx >> 4, iy = bx & 15;
  int n0 = ix * 256 + iy * 16;
#pragma unroll
  for (int it = 0; it < 8; ++it) {
    int idx = t + it * 256;
    int iz = idx >> 7, fq = idx & 127;
    ushort4 u = *(const ushort4*)(o2 + ((size_t)((n0 + iz) * 8 + b) * 512 + fq * 4));
    float4 v;
    v.x = bf2f(u.x); v.y = bf2f(u.y); v.z = bf2f(u.z); v.w = bf2f(u.w);
    *(float4*)(lds + iz * 516 + fq * 4) = v;
  }
  __syncthreads();
#pragma unroll
  for (int it = 0; it < 8; ++it) {
    int idx = t + it * 256;
    int fidx = idx >> 4, w4 = idx & 15;
    int c = fidx >> 4, px = (fidx >> 2) & 3, py = fidx & 3;
    int W0 = (w4 * 4 + 4) & 63;
    int pz = W0 >> 4, iz0 = W0 & 15;
    int fa = fidx * 4 + pz;
    float4 v;
    v.x = lds[(iz0 + 0) * 516 + fa];
    v.y = lds[(iz0 + 1) * 516 + fa];
    v.z = lds[(iz0 + 2) * 516 + fa];
    v.w = lds[(iz0 + 3) * 516 + fa];
    int uu = (px * 16 + ix + 60) & 63;
    int vv = (py * 16 + iy + 60) & 63;
    *(float4*)(out + ((((size_t)(b * 8 + c) * 64 + uu) * 64 + vv) * 64 + w4 * 4)) = v;
  }
}

// ---------------------------------------------------------------------------
extern "C" void kernel_launch(void* const* d_in, const int* in_sizes, int n_in,
                              void* d_out, int out_size, void* d_ws, size_t ws_size,
                              hipStream_t stream) {
  const float* x     = (const float*)d_in[0];
  const float* w_in  = (const float*)d_in[1];
  const float* b_in  = (const float*)d_in[2];
  const float* w_out = (const float*)d_in[3];
  const float* b_out = (const float*)d_in[4];
  float* out = (float*)d_out;

  char* ws = (char*)d_ws;
  u16* wq  = (u16*)(ws);                      // 1536*512 bf16
  u16* wo  = (u16*)(ws + 1572864);            // 512*512 bf16
  u16* xw2 = (u16*)(ws + 2097152);            // 32768*512 bf16, n-major rows
  u16* o   = (u16*)(ws + 35651584);           // 32768*512 bf16 (attn output)
  u16* o2  = (u16*)(ws + 69206016);           // 32768*512 bf16

  cast_both<<<1024, 256, 0, stream>>>(w_in, wq, w_out, wo);
  permute_in<<<dim3(256, 8), 256, 0, stream>>>(x, xw2);
  gemm_qkv_attn<<<2048, 256, 0, stream>>>(xw2, wq, b_in, o);
  gemm_out<<<512, 512, 0, stream>>>(o, wo, b_out, o2);
  permute_out<<<dim3(256, 8), 256, 0, stream>>>(o2, out);
}

// Round 9
// 246.450 us; speedup vs baseline: 1.3635x; 1.3635x over previous
//
#include <hip/hip_runtime.h>

typedef unsigned short u16;
typedef unsigned int u32;
typedef __bf16 bf16x8 __attribute__((ext_vector_type(8)));
typedef float f32x16 __attribute__((ext_vector_type(16)));

__device__ __forceinline__ u16 f2bf(float f) {
  u32 u = __builtin_bit_cast(u32, f);
  u = (u + 0x7FFFu + ((u >> 16) & 1u)) >> 16;
  return (u16)u;
}
__device__ __forceinline__ float bf2f(u16 h) {
  u32 u = ((u32)h) << 16;
  return __builtin_bit_cast(float, u);
}

#define GLD16(gp, lp) __builtin_amdgcn_global_load_lds( \
    (const __attribute__((address_space(1))) u32*)(const void*)(gp), \
    (__attribute__((address_space(3))) u32*)(void*)(lp), 16, 0, 0)
#define SBAR() __builtin_amdgcn_s_barrier()
#define SCHED0() __builtin_amdgcn_sched_barrier(0)

// ---------------------------------------------------------------------------
// both weight casts in one launch
__global__ __launch_bounds__(256) void cast_both(const float* __restrict__ w_in,
                                                 u16* __restrict__ wq,
                                                 const float* __restrict__ w_out,
                                                 u16* __restrict__ wo) {
  int i = blockIdx.x * 256 + threadIdx.x;
  const float* src = w_in; u16* dst = wq; int idx = i;
  if (i >= 196608) { src = w_out; dst = wo; idx = i - 196608; }
  float4 v = *(const float4*)(src + (size_t)idx * 4);
  ushort4 u;
  u.x = f2bf(v.x); u.y = f2bf(v.y); u.z = f2bf(v.z); u.w = f2bf(v.w);
  *(ushort4*)(dst + (size_t)idx * 4) = u;
}

// ---------------------------------------------------------------------------
// permute_in: x (B,C,64,64,64) fp32 -> xw rows n-major: row = nw*8 + b, col e
__global__ __launch_bounds__(256) void permute_in(const float* __restrict__ x,
                                                  u16* __restrict__ xw) {
  __shared__ float lds[128 * 64];
  int t = threadIdx.x;
  int bx = blockIdx.x;                 // jx*16 + jy
  int b = blockIdx.y;
  int jx = bx >> 4, jy = bx & 15;
#pragma unroll
  for (int it = 0; it < 8; ++it) {
    int idx = t + it * 256;
    int row = idx >> 4, z4 = idx & 15;
    int c = row >> 4, qx = (row >> 2) & 3, qy = row & 3;
    int X = (jx * 4 + qx + 60) & 63;
    int Y = (jy * 4 + qy + 60) & 63;
    float4 v = *(const float4*)(x + ((((size_t)(b * 8 + c) * 64 + X) * 64 + Y) * 64 + z4 * 4));
    *(float4*)(lds + row * 64 + ((z4 ^ (row & 7)) << 2)) = v;
  }
  __syncthreads();
#pragma unroll
  for (int it = 0; it < 8; ++it) {
    int idx = t + it * 256;
    int jz = idx >> 7, r = idx & 127;
    int z4r = (jz + 15) & 15;
    float4 v = *(const float4*)(lds + r * 64 + ((z4r ^ (r & 7)) << 2));
    int nw = jx * 256 + jy * 16 + jz;
    ushort4 u;
    u.x = f2bf(v.x); u.y = f2bf(v.y); u.z = f2bf(v.z); u.w = f2bf(v.w);
    *(ushort4*)(xw + (size_t)(nw * 8 + b) * 512 + r * 4) = u;
  }
}

// ---------------------------------------------------------------------------
// Fused QKV GEMM + attention. Block = 128 rows x 192 cols (Q|K|V of head h),
// 256 threads (4 waves, 2x2), 32x32x16 MFMA, BK=32 double-buffer.
// Row-pair LDS swizzle (chunkslot = chunk ^ ((row>>1)&3)): fragment
// ds_read_b128 phase covers all 8 bank-quads. fp32 attention ctile aliased
// onto dead staging LDS. launch_bounds (256,3): 3 waves/SIMD keeps the
// ~160-reg footprint (96 AGPR acc) un-spilled  (r8 lesson: (256,4) -> spill).
__global__ __launch_bounds__(256, 3) void gemm_qkv_attn(const u16* __restrict__ A,
                                                        const u16* __restrict__ W,
                                                        const float* __restrict__ bias,
                                                        u16* __restrict__ O) {
  __shared__ u16 smem[20480];  // 40960 B: As[2][4096] + Bs[2][6144]; ctf aliases
  u16* As = smem;
  u16* Bs = smem + 8192;
  float* ctf = (float*)smem;   // [32][204] f32 = 26112 B (epilogue only)

  int cpx = gridDim.x >> 3;    // 2048/8 = 256
  int wg = (blockIdx.x & 7) * cpx + (blockIdx.x >> 3);
  int mbc = wg >> 3, h = wg & 7;
  int m0 = mbc * 128;

  int tid = threadIdx.x;
  int wv = tid >> 6, l = tid & 63;
  int wr = wv >> 1, wc = wv & 1;
  int l31 = l & 31, g = l >> 5;

  // staging: slot s -> row = s>>2, chunkslot = s&3 holds data chunk (s&3)^((s>>3)&3)
  int kch = ((l & 3) ^ ((l >> 3) & 3)) * 8;
  const u16* pa[2]; int dA[2];
#pragma unroll
  for (int i = 0; i < 2; ++i) {
    int slot = wv * 128 + i * 64 + l;
    int row = slot >> 2;                     // 0..127
    pa[i] = A + (size_t)(m0 + row) * 512 + kch;
    dA[i] = (wv * 128 + i * 64) * 8;
  }
  const u16* pb[3]; int dB[3];
#pragma unroll
  for (int i = 0; i < 3; ++i) {
    int slot = wv * 192 + i * 64 + l;
    int row = slot >> 2;                     // 0..191
    int grow = (row >> 6) * 512 + h * 64 + (row & 63);
    pb[i] = W + (size_t)grow * 512 + kch;
    dB[i] = (wv * 192 + i * 64) * 8;
  }

  int abase[2], bbase[3];
#pragma unroll
  for (int m = 0; m < 2; ++m) abase[m] = (wr * 64 + m * 32 + l31) * 32;
#pragma unroll
  for (int n = 0; n < 3; ++n) bbase[n] = (wc * 96 + n * 32 + l31) * 32;
  int rsw = (l31 >> 1) & 3;    // row-pair swizzle bits for fragment reads

  f32x16 acc[2][3] = {};

  // prologue: stage tile 0 -> buf 0
  GLD16(pa[0], As + dA[0]); GLD16(pa[1], As + dA[1]);
  GLD16(pb[0], Bs + dB[0]); GLD16(pb[1], Bs + dB[1]); GLD16(pb[2], Bs + dB[2]);
  asm volatile("s_waitcnt vmcnt(0)" ::: "memory");
  SCHED0(); SBAR(); SCHED0();

  for (int t = 0; t < 16; ++t) {
    const u16* AsT = As + (t & 1) * 4096;
    const u16* BsT = Bs + (t & 1) * 6144;
    u16* Ad = As + ((t + 1) & 1) * 4096;
    u16* Bd = Bs + ((t + 1) & 1) * 6144;
    int nx = (t + 1) * 32;
    bool st = t < 15;
#pragma unroll
    for (int s = 0; s < 2; ++s) {
      int cofs = ((((s << 1) | g) ^ rsw)) << 3;
      bf16x8 af[2], bf[3];
      af[0] = *(const bf16x8*)(AsT + abase[0] + cofs);
      af[1] = *(const bf16x8*)(AsT + abase[1] + cofs);
      bf[0] = *(const bf16x8*)(BsT + bbase[0] + cofs);
      bf[1] = *(const bf16x8*)(BsT + bbase[1] + cofs);
      bf[2] = *(const bf16x8*)(BsT + bbase[2] + cofs);
      if (s == 0 && st) { GLD16(pa[0] + nx, Ad + dA[0]); GLD16(pa[1] + nx, Ad + dA[1]); }
      if (s == 1 && st) {
        GLD16(pb[0] + nx, Bd + dB[0]); GLD16(pb[1] + nx, Bd + dB[1]);
        GLD16(pb[2] + nx, Bd + dB[2]);
      }
      SCHED0();
      __builtin_amdgcn_s_setprio(1);
#pragma unroll
      for (int m = 0; m < 2; ++m)
#pragma unroll
        for (int n = 0; n < 3; ++n)
          acc[m][n] = __builtin_amdgcn_mfma_f32_32x32x16_bf16(bf[n], af[m], acc[m][n], 0, 0, 0);
      __builtin_amdgcn_s_setprio(0);
      SCHED0();
    }
    asm volatile("s_waitcnt vmcnt(0)" ::: "memory");
    SCHED0(); SBAR(); SCHED0();
  }

  // ---- chunked epilogue: 4 chunks of 32 rows; fp32 ctile, no bf16 round-trip
#pragma unroll 1
  for (int c = 0; c < 4; ++c) {
    if ((c >> 1) == wr) {
      int m = c & 1;
#pragma unroll
      for (int n = 0; n < 3; ++n)
#pragma unroll
        for (int q = 0; q < 4; ++q) {
          int col0 = wc * 96 + n * 32 + q * 8 + g * 4;
          int gcol = ((col0 >> 6) << 9) + (h << 6) + (col0 & 63);
          float4 bv = *(const float4*)(bias + gcol);
          float4 stv;
          stv.x = acc[m][n][q * 4 + 0] + bv.x;
          stv.y = acc[m][n][q * 4 + 1] + bv.y;
          stv.z = acc[m][n][q * 4 + 2] + bv.z;
          stv.w = acc[m][n][q * 4 + 3] + bv.w;
          *(float4*)(ctf + l31 * 204 + col0) = stv;
        }
    }
    __syncthreads();
    // attention: wave wv handles window wv of this chunk (8 rows)
    {
      int qi = l >> 3, j = l & 7;
      const float* qr = ctf + (wv * 8 + qi) * 204;
      const float* kr = ctf + (wv * 8 + j) * 204 + 64;
      float sc = 0.f;
#pragma unroll
      for (int d = 0; d < 16; ++d) {
        float4 qv = *(const float4*)(qr + d * 4);
        float4 kv = *(const float4*)(kr + d * 4);
        sc += qv.x * kv.x + qv.y * kv.y + qv.z * kv.z + qv.w * kv.w;
      }
      sc *= 0.125f;
      float mx = sc;
      mx = fmaxf(mx, __shfl_xor(mx, 1));
      mx = fmaxf(mx, __shfl_xor(mx, 2));
      mx = fmaxf(mx, __shfl_xor(mx, 4));
      float p = __expf(sc - mx);
      float sum = p;
      sum += __shfl_xor(sum, 1);
      sum += __shfl_xor(sum, 2);
      sum += __shfl_xor(sum, 4);
      p /= sum;
      float pr[8];
      int lb = l & 56;
#pragma unroll
      for (int jj = 0; jj < 8; ++jj) pr[jj] = __shfl(p, lb + jj);
      float ov[8] = {};
#pragma unroll
      for (int jj = 0; jj < 8; ++jj) {
        const float* vr = ctf + (wv * 8 + jj) * 204 + 128 + j * 8;
        float4 va = *(const float4*)(vr);
        float4 vb = *(const float4*)(vr + 4);
        float pj = pr[jj];
        ov[0] += pj * va.x; ov[1] += pj * va.y; ov[2] += pj * va.z; ov[3] += pj * va.w;
        ov[4] += pj * vb.x; ov[5] += pj * vb.y; ov[6] += pj * vb.z; ov[7] += pj * vb.w;
      }
      ushort4 r0, r1;
      r0.x = f2bf(ov[0]); r0.y = f2bf(ov[1]); r0.z = f2bf(ov[2]); r0.w = f2bf(ov[3]);
      r1.x = f2bf(ov[4]); r1.y = f2bf(ov[5]); r1.z = f2bf(ov[6]); r1.w = f2bf(ov[7]);
      u16* dst = O + (size_t)(m0 + c * 32 + wv * 8 + qi) * 512 + h * 64 + j * 8;
      *(ushort4*)dst = r0;
      *(ushort4*)(dst + 4) = r1;
    }
    __syncthreads();
  }
}

// ---------------------------------------------------------------------------
// out-proj GEMM: C[32768,512] = o @ wo^T + bias. Block 256x128, 512 thr
// (8 waves, 4x2), 32x32x16 MFMA, BK=32, row-pair swizzle, grid 512.
__global__ __launch_bounds__(512, 4) void gemm_out(const u16* __restrict__ A,
                                                   const u16* __restrict__ Wt,
                                                   const float* __restrict__ bias,
                                                   u16* __restrict__ C) {
  __shared__ u16 smem[24576];
  u16* As = smem;            // [2][8192]  (256 rows x 32 k)
  u16* Bs = smem + 16384;    // [2][4096]  (128 rows x 32 k)

  int cpx = gridDim.x >> 3;  // 512/8 = 64
  int wg = (blockIdx.x & 7) * cpx + (blockIdx.x >> 3);
  int mb = wg >> 2, nb = wg & 3;
  int m0 = mb * 256, n0 = nb * 128;

  int tid = threadIdx.x;
  int wv = tid >> 6, l = tid & 63;
  int wr = wv >> 1, wc = wv & 1;
  int l31 = l & 31, g = l >> 5;

  int kch = ((l & 3) ^ ((l >> 3) & 3)) * 8;
  const u16* pa[2]; int dA[2];
#pragma unroll
  for (int i = 0; i < 2; ++i) {
    int slot = wv * 128 + i * 64 + l;
    int row = slot >> 2;                     // 0..255
    pa[i] = A + (size_t)(m0 + row) * 512 + kch;
    dA[i] = (wv * 128 + i * 64) * 8;
  }
  int slotB = wv * 64 + l;
  int rowB = slotB >> 2;                     // 0..127
  const u16* pb = Wt + (size_t)(n0 + rowB) * 512 + kch;
  int dB = (wv * 64) * 8;

  int abase[2], bbase[2];
#pragma unroll
  for (int m = 0; m < 2; ++m) abase[m] = (wr * 64 + m * 32 + l31) * 32;
#pragma unroll
  for (int n = 0; n < 2; ++n) bbase[n] = (wc * 64 + n * 32 + l31) * 32;
  int rsw = (l31 >> 1) & 3;

  f32x16 acc[2][2] = {};

  GLD16(pa[0], As + dA[0]); GLD16(pa[1], As + dA[1]);
  GLD16(pb, Bs + dB);
  asm volatile("s_waitcnt vmcnt(0)" ::: "memory");
  SCHED0(); SBAR(); SCHED0();

  for (int t = 0; t < 16; ++t) {
    const u16* AsT = As + (t & 1) * 8192;
    const u16* BsT = Bs + (t & 1) * 4096;
    u16* Ad = As + ((t + 1) & 1) * 8192;
    u16* Bd = Bs + ((t + 1) & 1) * 4096;
    int nx = (t + 1) * 32;
    bool st = t < 15;
#pragma unroll
    for (int s = 0; s < 2; ++s) {
      int cofs = ((((s << 1) | g) ^ rsw)) << 3;
      bf16x8 af[2], bf[2];
      af[0] = *(const bf16x8*)(AsT + abase[0] + cofs);
      af[1] = *(const bf16x8*)(AsT + abase[1] + cofs);
      bf[0] = *(const bf16x8*)(BsT + bbase[0] + cofs);
      bf[1] = *(const bf16x8*)(BsT + bbase[1] + cofs);
      if (s == 0 && st) { GLD16(pa[0] + nx, Ad + dA[0]); GLD16(pa[1] + nx, Ad + dA[1]); }
      if (s == 1 && st) { GLD16(pb + nx, Bd + dB); }
      SCHED0();
      __builtin_amdgcn_s_setprio(1);
#pragma unroll
      for (int m = 0; m < 2; ++m)
#pragma unroll
        for (int n = 0; n < 2; ++n)
          acc[m][n] = __builtin_amdgcn_mfma_f32_32x32x16_bf16(bf[n], af[m], acc[m][n], 0, 0, 0);
      __builtin_amdgcn_s_setprio(0);
      SCHED0();
    }
    asm volatile("s_waitcnt vmcnt(0)" ::: "memory");
    SCHED0(); SBAR(); SCHED0();
  }

#pragma unroll
  for (int m = 0; m < 2; ++m) {
    size_t row = (size_t)(m0 + wr * 64 + m * 32 + l31);
#pragma unroll
    for (int n = 0; n < 2; ++n)
#pragma unroll
      for (int q = 0; q < 4; ++q) {
        int col0 = n0 + wc * 64 + n * 32 + q * 8 + g * 4;
        float4 bv = *(const float4*)(bias + col0);
        ushort4 uu;
        uu.x = f2bf(acc[m][n][q * 4 + 0] + bv.x);
        uu.y = f2bf(acc[m][n][q * 4 + 1] + bv.y);
        uu.z = f2bf(acc[m][n][q * 4 + 2] + bv.z);
        uu.w = f2bf(acc[m][n][q * 4 + 3] + bv.w);
        *(ushort4*)(C + row * 512 + col0) = uu;
      }
  }
}

// ---------------------------------------------------------------------------
// permute_out: o2 rows n-major (row = n*8+b) bf16 -> out (B,C,64,64,64) fp32
__global__ __launch_bounds__(256) void permute_out(const u16* __restrict__ o2,
                                                   float* __restrict__ out) {
  __shared__ float lds[16 * 516];
  int t = threadIdx.x;
  int bx = blockIdx.x;
  int b = blockIdx.y;
  int ix = bx >> 4, iy = bx & 15;
  int n0 = ix * 256 + iy * 16;
#pragma unroll
  for (int it = 0; it < 8; ++it) {
    int idx = t + it * 256;
    int iz = idx >> 7, fq = idx & 127;
    ushort4 u = *(const ushort4*)(o2 + ((size_t)((n0 + iz) * 8 + b) * 512 + fq * 4));
    float4 v;
    v.x = bf2f(u.x); v.y = bf2f(u.y); v.z = bf2f(u.z); v.w = bf2f(u.w);
    *(float4*)(lds + iz * 516 + fq * 4) = v;
  }
  __syncthreads();
#pragma unroll
  for (int it = 0; it < 8; ++it) {
    int idx = t + it * 256;
    int fidx = idx >> 4, w4 = idx & 15;
    int c = fidx >> 4, px = (fidx >> 2) & 3, py = fidx & 3;
    int W0 = (w4 * 4 + 4) & 63;
    int pz = W0 >> 4, iz0 = W0 & 15;
    int fa = fidx * 4 + pz;
    float4 v;
    v.x = lds[(iz0 + 0) * 516 + fa];
    v.y = lds[(iz0 + 1) * 516 + fa];
    v.z = lds[(iz0 + 2) * 516 + fa];
    v.w = lds[(iz0 + 3) * 516 + fa];
    int uu = (px * 16 + ix + 60) & 63;
    int vv = (py * 16 + iy + 60) & 63;
    *(float4*)(out + ((((size_t)(b * 8 + c) * 64 + uu) * 64 + vv) * 64 + w4 * 4)) = v;
  }
}

// ---------------------------------------------------------------------------
extern "C" void kernel_launch(void* const* d_in, const int* in_sizes, int n_in,
                              void* d_out, int out_size, void* d_ws, size_t ws_size,
                              hipStream_t stream) {
  const float* x     = (const float*)d_in[0];
  const float* w_in  = (const float*)d_in[1];
  const float* b_in  = (const float*)d_in[2];
  const float* w_out = (const float*)d_in[3];
  const float* b_out = (const float*)d_in[4];
  float* out = (float*)d_out;

  char* ws = (char*)d_ws;
  u16* wq  = (u16*)(ws);                      // 1536*512 bf16
  u16* wo  = (u16*)(ws + 1572864);            // 512*512 bf16
  u16* xw2 = (u16*)(ws + 2097152);            // 32768*512 bf16, n-major rows
  u16* o   = (u16*)(ws + 35651584);           // 32768*512 bf16 (attn output)
  u16* o2  = (u16*)(ws + 69206016);           // 32768*512 bf16

  cast_both<<<1024, 256, 0, stream>>>(w_in, wq, w_out, wo);
  permute_in<<<dim3(256, 8), 256, 0, stream>>>(x, xw2);
  gemm_qkv_attn<<<2048, 256, 0, stream>>>(xw2, wq, b_in, o);
  gemm_out<<<512, 512, 0, stream>>>(o, wo, b_out, o2);
  permute_out<<<dim3(256, 8), 256, 0, stream>>>(o2, out);
}

// Round 10
// 157.706 us; speedup vs baseline: 2.1308x; 1.5627x over previous
//
#include <hip/hip_runtime.h>

typedef unsigned short u16;
typedef unsigned int u32;
typedef __bf16 bf16x8 __attribute__((ext_vector_type(8)));
typedef float f32x16 __attribute__((ext_vector_type(16)));

__device__ __forceinline__ u16 f2bf(float f) {
  u32 u = __builtin_bit_cast(u32, f);
  u = (u + 0x7FFFu + ((u >> 16) & 1u)) >> 16;
  return (u16)u;
}
__device__ __forceinline__ float bf2f(u16 h) {
  u32 u = ((u32)h) << 16;
  return __builtin_bit_cast(float, u);
}

#define GLD16(gp, lp) __builtin_amdgcn_global_load_lds( \
    (const __attribute__((address_space(1))) u32*)(const void*)(gp), \
    (__attribute__((address_space(3))) u32*)(void*)(lp), 16, 0, 0)
#define SBAR() __builtin_amdgcn_s_barrier()
#define SCHED0() __builtin_amdgcn_sched_barrier(0)

// ---------------------------------------------------------------------------
// both weight casts in one launch
__global__ __launch_bounds__(256) void cast_both(const float* __restrict__ w_in,
                                                 u16* __restrict__ wq,
                                                 const float* __restrict__ w_out,
                                                 u16* __restrict__ wo) {
  int i = blockIdx.x * 256 + threadIdx.x;
  const float* src = w_in; u16* dst = wq; int idx = i;
  if (i >= 196608) { src = w_out; dst = wo; idx = i - 196608; }
  float4 v = *(const float4*)(src + (size_t)idx * 4);
  ushort4 u;
  u.x = f2bf(v.x); u.y = f2bf(v.y); u.z = f2bf(v.z); u.w = f2bf(v.w);
  *(ushort4*)(dst + (size_t)idx * 4) = u;
}

// ---------------------------------------------------------------------------
// permute_in: x (B,C,64,64,64) fp32 -> xw rows n-major: row = nw*8 + b, col e
__global__ __launch_bounds__(256) void permute_in(const float* __restrict__ x,
                                                  u16* __restrict__ xw) {
  __shared__ float lds[128 * 64];
  int t = threadIdx.x;
  int bx = blockIdx.x;                 // jx*16 + jy
  int b = blockIdx.y;
  int jx = bx >> 4, jy = bx & 15;
#pragma unroll
  for (int it = 0; it < 8; ++it) {
    int idx = t + it * 256;
    int row = idx >> 4, z4 = idx & 15;
    int c = row >> 4, qx = (row >> 2) & 3, qy = row & 3;
    int X = (jx * 4 + qx + 60) & 63;
    int Y = (jy * 4 + qy + 60) & 63;
    float4 v = *(const float4*)(x + ((((size_t)(b * 8 + c) * 64 + X) * 64 + Y) * 64 + z4 * 4));
    *(float4*)(lds + row * 64 + ((z4 ^ (row & 7)) << 2)) = v;
  }
  __syncthreads();
#pragma unroll
  for (int it = 0; it < 8; ++it) {
    int idx = t + it * 256;
    int jz = idx >> 7, r = idx & 127;
    int z4r = (jz + 15) & 15;
    float4 v = *(const float4*)(lds + r * 64 + ((z4r ^ (r & 7)) << 2));
    int nw = jx * 256 + jy * 16 + jz;
    ushort4 u;
    u.x = f2bf(v.x); u.y = f2bf(v.y); u.z = f2bf(v.z); u.w = f2bf(v.w);
    *(ushort4*)(xw + (size_t)(nw * 8 + b) * 512 + r * 4) = u;
  }
}

// ---------------------------------------------------------------------------
// Fused QKV GEMM + attention. Block = 128 rows x 192 cols (Q|K|V of head h),
// 256 threads (4 waves, 2x2), 32x32x16 MFMA, BK=32 double-buffer.
// Row-pair LDS swizzle (chunkslot = chunk ^ ((row>>1)&3)): fragment
// ds_read_b128 phase covers all 8 bank-quads. fp32 attention ctile aliased
// onto dead staging LDS. Chunk epilogue loop MUST be fully unrolled: runtime
// index into acc[][] sends the whole accumulator to scratch (rule #20 —
// r8/r9's 600 MB WRITE_SIZE regression).
__global__ __launch_bounds__(256, 3) void gemm_qkv_attn(const u16* __restrict__ A,
                                                        const u16* __restrict__ W,
                                                        const float* __restrict__ bias,
                                                        u16* __restrict__ O) {
  __shared__ u16 smem[20480];  // 40960 B: As[2][4096] + Bs[2][6144]; ctf aliases
  u16* As = smem;
  u16* Bs = smem + 8192;
  float* ctf = (float*)smem;   // [32][204] f32 = 26112 B (epilogue only)

  int cpx = gridDim.x >> 3;    // 2048/8 = 256
  int wg = (blockIdx.x & 7) * cpx + (blockIdx.x >> 3);
  int mbc = wg >> 3, h = wg & 7;
  int m0 = mbc * 128;

  int tid = threadIdx.x;
  int wv = tid >> 6, l = tid & 63;
  int wr = wv >> 1, wc = wv & 1;
  int l31 = l & 31, g = l >> 5;

  // staging: slot s -> row = s>>2, chunkslot = s&3 holds data chunk (s&3)^((s>>3)&3)
  int kch = ((l & 3) ^ ((l >> 3) & 3)) * 8;
  const u16* pa[2]; int dA[2];
#pragma unroll
  for (int i = 0; i < 2; ++i) {
    int slot = wv * 128 + i * 64 + l;
    int row = slot >> 2;                     // 0..127
    pa[i] = A + (size_t)(m0 + row) * 512 + kch;
    dA[i] = (wv * 128 + i * 64) * 8;
  }
  const u16* pb[3]; int dB[3];
#pragma unroll
  for (int i = 0; i < 3; ++i) {
    int slot = wv * 192 + i * 64 + l;
    int row = slot >> 2;                     // 0..191
    int grow = (row >> 6) * 512 + h * 64 + (row & 63);
    pb[i] = W + (size_t)grow * 512 + kch;
    dB[i] = (wv * 192 + i * 64) * 8;
  }

  int abase[2], bbase[3];
#pragma unroll
  for (int m = 0; m < 2; ++m) abase[m] = (wr * 64 + m * 32 + l31) * 32;
#pragma unroll
  for (int n = 0; n < 3; ++n) bbase[n] = (wc * 96 + n * 32 + l31) * 32;
  int rsw = (l31 >> 1) & 3;    // row-pair swizzle bits for fragment reads

  f32x16 acc[2][3] = {};

  // prologue: stage tile 0 -> buf 0
  GLD16(pa[0], As + dA[0]); GLD16(pa[1], As + dA[1]);
  GLD16(pb[0], Bs + dB[0]); GLD16(pb[1], Bs + dB[1]); GLD16(pb[2], Bs + dB[2]);
  asm volatile("s_waitcnt vmcnt(0)" ::: "memory");
  SCHED0(); SBAR(); SCHED0();

  for (int t = 0; t < 16; ++t) {
    const u16* AsT = As + (t & 1) * 4096;
    const u16* BsT = Bs + (t & 1) * 6144;
    u16* Ad = As + ((t + 1) & 1) * 4096;
    u16* Bd = Bs + ((t + 1) & 1) * 6144;
    int nx = (t + 1) * 32;
    bool st = t < 15;
#pragma unroll
    for (int s = 0; s < 2; ++s) {
      int cofs = ((((s << 1) | g) ^ rsw)) << 3;
      bf16x8 af[2], bf[3];
      af[0] = *(const bf16x8*)(AsT + abase[0] + cofs);
      af[1] = *(const bf16x8*)(AsT + abase[1] + cofs);
      bf[0] = *(const bf16x8*)(BsT + bbase[0] + cofs);
      bf[1] = *(const bf16x8*)(BsT + bbase[1] + cofs);
      bf[2] = *(const bf16x8*)(BsT + bbase[2] + cofs);
      if (s == 0 && st) { GLD16(pa[0] + nx, Ad + dA[0]); GLD16(pa[1] + nx, Ad + dA[1]); }
      if (s == 1 && st) {
        GLD16(pb[0] + nx, Bd + dB[0]); GLD16(pb[1] + nx, Bd + dB[1]);
        GLD16(pb[2] + nx, Bd + dB[2]);
      }
      SCHED0();
      __builtin_amdgcn_s_setprio(1);
#pragma unroll
      for (int m = 0; m < 2; ++m)
#pragma unroll
        for (int n = 0; n < 3; ++n)
          acc[m][n] = __builtin_amdgcn_mfma_f32_32x32x16_bf16(bf[n], af[m], acc[m][n], 0, 0, 0);
      __builtin_amdgcn_s_setprio(0);
      SCHED0();
    }
    asm volatile("s_waitcnt vmcnt(0)" ::: "memory");
    SCHED0(); SBAR(); SCHED0();
  }

  // ---- chunked epilogue: 4 chunks of 32 rows; fp32 ctile. FULLY UNROLLED
  // (static acc indices — rule #20).
#pragma unroll
  for (int c = 0; c < 4; ++c) {
    if ((c >> 1) == wr) {
      const int m = c & 1;
#pragma unroll
      for (int n = 0; n < 3; ++n)
#pragma unroll
        for (int q = 0; q < 4; ++q) {
          int col0 = wc * 96 + n * 32 + q * 8 + g * 4;
          int gcol = ((col0 >> 6) << 9) + (h << 6) + (col0 & 63);
          float4 bv = *(const float4*)(bias + gcol);
          float4 stv;
          stv.x = acc[m][n][q * 4 + 0] + bv.x;
          stv.y = acc[m][n][q * 4 + 1] + bv.y;
          stv.z = acc[m][n][q * 4 + 2] + bv.z;
          stv.w = acc[m][n][q * 4 + 3] + bv.w;
          *(float4*)(ctf + l31 * 204 + col0) = stv;
        }
    }
    __syncthreads();
    // attention: wave wv handles window wv of this chunk (8 rows)
    {
      int qi = l >> 3, j = l & 7;
      const float* qr = ctf + (wv * 8 + qi) * 204;
      const float* kr = ctf + (wv * 8 + j) * 204 + 64;
      float sc = 0.f;
#pragma unroll
      for (int d = 0; d < 16; ++d) {
        float4 qv = *(const float4*)(qr + d * 4);
        float4 kv = *(const float4*)(kr + d * 4);
        sc += qv.x * kv.x + qv.y * kv.y + qv.z * kv.z + qv.w * kv.w;
      }
      sc *= 0.125f;
      float mx = sc;
      mx = fmaxf(mx, __shfl_xor(mx, 1));
      mx = fmaxf(mx, __shfl_xor(mx, 2));
      mx = fmaxf(mx, __shfl_xor(mx, 4));
      float p = __expf(sc - mx);
      float sum = p;
      sum += __shfl_xor(sum, 1);
      sum += __shfl_xor(sum, 2);
      sum += __shfl_xor(sum, 4);
      p /= sum;
      float pr[8];
      int lb = l & 56;
#pragma unroll
      for (int jj = 0; jj < 8; ++jj) pr[jj] = __shfl(p, lb + jj);
      float ov[8] = {};
#pragma unroll
      for (int jj = 0; jj < 8; ++jj) {
        const float* vr = ctf + (wv * 8 + jj) * 204 + 128 + j * 8;
        float4 va = *(const float4*)(vr);
        float4 vb = *(const float4*)(vr + 4);
        float pj = pr[jj];
        ov[0] += pj * va.x; ov[1] += pj * va.y; ov[2] += pj * va.z; ov[3] += pj * va.w;
        ov[4] += pj * vb.x; ov[5] += pj * vb.y; ov[6] += pj * vb.z; ov[7] += pj * vb.w;
      }
      ushort4 r0, r1;
      r0.x = f2bf(ov[0]); r0.y = f2bf(ov[1]); r0.z = f2bf(ov[2]); r0.w = f2bf(ov[3]);
      r1.x = f2bf(ov[4]); r1.y = f2bf(ov[5]); r1.z = f2bf(ov[6]); r1.w = f2bf(ov[7]);
      u16* dst = O + (size_t)(m0 + c * 32 + wv * 8 + qi) * 512 + h * 64 + j * 8;
      *(ushort4*)dst = r0;
      *(ushort4*)(dst + 4) = r1;
    }
    __syncthreads();
  }
}

// ---------------------------------------------------------------------------
// out-proj GEMM: C[32768,512] = o @ wo^T + bias. Block 256x128, 512 thr
// (8 waves, 4x2), 32x32x16 MFMA, BK=32, row-pair swizzle, grid 512.
__global__ __launch_bounds__(512, 4) void gemm_out(const u16* __restrict__ A,
                                                   const u16* __restrict__ Wt,
                                                   const float* __restrict__ bias,
                                                   u16* __restrict__ C) {
  __shared__ u16 smem[24576];
  u16* As = smem;            // [2][8192]  (256 rows x 32 k)
  u16* Bs = smem + 16384;    // [2][4096]  (128 rows x 32 k)

  int cpx = gridDim.x >> 3;  // 512/8 = 64
  int wg = (blockIdx.x & 7) * cpx + (blockIdx.x >> 3);
  int mb = wg >> 2, nb = wg & 3;
  int m0 = mb * 256, n0 = nb * 128;

  int tid = threadIdx.x;
  int wv = tid >> 6, l = tid & 63;
  int wr = wv >> 1, wc = wv & 1;
  int l31 = l & 31, g = l >> 5;

  int kch = ((l & 3) ^ ((l >> 3) & 3)) * 8;
  const u16* pa[2]; int dA[2];
#pragma unroll
  for (int i = 0; i < 2; ++i) {
    int slot = wv * 128 + i * 64 + l;
    int row = slot >> 2;                     // 0..255
    pa[i] = A + (size_t)(m0 + row) * 512 + kch;
    dA[i] = (wv * 128 + i * 64) * 8;
  }
  int slotB = wv * 64 + l;
  int rowB = slotB >> 2;                     // 0..127
  const u16* pb = Wt + (size_t)(n0 + rowB) * 512 + kch;
  int dB = (wv * 64) * 8;

  int abase[2], bbase[2];
#pragma unroll
  for (int m = 0; m < 2; ++m) abase[m] = (wr * 64 + m * 32 + l31) * 32;
#pragma unroll
  for (int n = 0; n < 2; ++n) bbase[n] = (wc * 64 + n * 32 + l31) * 32;
  int rsw = (l31 >> 1) & 3;

  f32x16 acc[2][2] = {};

  GLD16(pa[0], As + dA[0]); GLD16(pa[1], As + dA[1]);
  GLD16(pb, Bs + dB);
  asm volatile("s_waitcnt vmcnt(0)" ::: "memory");
  SCHED0(); SBAR(); SCHED0();

  for (int t = 0; t < 16; ++t) {
    const u16* AsT = As + (t & 1) * 8192;
    const u16* BsT = Bs + (t & 1) * 4096;
    u16* Ad = As + ((t + 1) & 1) * 8192;
    u16* Bd = Bs + ((t + 1) & 1) * 4096;
    int nx = (t + 1) * 32;
    bool st = t < 15;
#pragma unroll
    for (int s = 0; s < 2; ++s) {
      int cofs = ((((s << 1) | g) ^ rsw)) << 3;
      bf16x8 af[2], bf[2];
      af[0] = *(const bf16x8*)(AsT + abase[0] + cofs);
      af[1] = *(const bf16x8*)(AsT + abase[1] + cofs);
      bf[0] = *(const bf16x8*)(BsT + bbase[0] + cofs);
      bf[1] = *(const bf16x8*)(BsT + bbase[1] + cofs);
      if (s == 0 && st) { GLD16(pa[0] + nx, Ad + dA[0]); GLD16(pa[1] + nx, Ad + dA[1]); }
      if (s == 1 && st) { GLD16(pb + nx, Bd + dB); }
      SCHED0();
      __builtin_amdgcn_s_setprio(1);
#pragma unroll
      for (int m = 0; m < 2; ++m)
#pragma unroll
        for (int n = 0; n < 2; ++n)
          acc[m][n] = __builtin_amdgcn_mfma_f32_32x32x16_bf16(bf[n], af[m], acc[m][n], 0, 0, 0);
      __builtin_amdgcn_s_setprio(0);
      SCHED0();
    }
    asm volatile("s_waitcnt vmcnt(0)" ::: "memory");
    SCHED0(); SBAR(); SCHED0();
  }

#pragma unroll
  for (int m = 0; m < 2; ++m) {
    size_t row = (size_t)(m0 + wr * 64 + m * 32 + l31);
#pragma unroll
    for (int n = 0; n < 2; ++n)
#pragma unroll
      for (int q = 0; q < 4; ++q) {
        int col0 = n0 + wc * 64 + n * 32 + q * 8 + g * 4;
        float4 bv = *(const float4*)(bias + col0);
        ushort4 uu;
        uu.x = f2bf(acc[m][n][q * 4 + 0] + bv.x);
        uu.y = f2bf(acc[m][n][q * 4 + 1] + bv.y);
        uu.z = f2bf(acc[m][n][q * 4 + 2] + bv.z);
        uu.w = f2bf(acc[m][n][q * 4 + 3] + bv.w);
        *(ushort4*)(C + row * 512 + col0) = uu;
      }
  }
}

// ---------------------------------------------------------------------------
// permute_out: o2 rows n-major (row = n*8+b) bf16 -> out (B,C,64,64,64) fp32
__global__ __launch_bounds__(256) void permute_out(const u16* __restrict__ o2,
                                                   float* __restrict__ out) {
  __shared__ float lds[16 * 516];
  int t = threadIdx.x;
  int bx = blockIdx.x;
  int b = blockIdx.y;
  int ix = bx >> 4, iy = bx & 15;
  int n0 = ix * 256 + iy * 16;
#pragma unroll
  for (int it = 0; it < 8; ++it) {
    int idx = t + it * 256;
    int iz = idx >> 7, fq = idx & 127;
    ushort4 u = *(const ushort4*)(o2 + ((size_t)((n0 + iz) * 8 + b) * 512 + fq * 4));
    float4 v;
    v.x = bf2f(u.x); v.y = bf2f(u.y); v.z = bf2f(u.z); v.w = bf2f(u.w);
    *(float4*)(lds + iz * 516 + fq * 4) = v;
  }
  __syncthreads();
#pragma unroll
  for (int it = 0; it < 8; ++it) {
    int idx = t + it * 256;
    int fidx = idx >> 4, w4 = idx & 15;
    int c = fidx >> 4, px = (fidx >> 2) & 3, py = fidx & 3;
    int W0 = (w4 * 4 + 4) & 63;
    int pz = W0 >> 4, iz0 = W0 & 15;
    int fa = fidx * 4 + pz;
    float4 v;
    v.x = lds[(iz0 + 0) * 516 + fa];
    v.y = lds[(iz0 + 1) * 516 + fa];
    v.z = lds[(iz0 + 2) * 516 + fa];
    v.w = lds[(iz0 + 3) * 516 + fa];
    int uu = (px * 16 + ix + 60) & 63;
    int vv = (py * 16 + iy + 60) & 63;
    *(float4*)(out + ((((size_t)(b * 8 + c) * 64 + uu) * 64 + vv) * 64 + w4 * 4)) = v;
  }
}

// ---------------------------------------------------------------------------
extern "C" void kernel_launch(void* const* d_in, const int* in_sizes, int n_in,
                              void* d_out, int out_size, void* d_ws, size_t ws_size,
                              hipStream_t stream) {
  const float* x     = (const float*)d_in[0];
  const float* w_in  = (const float*)d_in[1];
  const float* b_in  = (const float*)d_in[2];
  const float* w_out = (const float*)d_in[3];
  const float* b_out = (const float*)d_in[4];
  float* out = (float*)d_out;

  char* ws = (char*)d_ws;
  u16* wq  = (u16*)(ws);                      // 1536*512 bf16
  u16* wo  = (u16*)(ws + 1572864);            // 512*512 bf16
  u16* xw2 = (u16*)(ws + 2097152);            // 32768*512 bf16, n-major rows
  u16* o   = (u16*)(ws + 35651584);           // 32768*512 bf16 (attn output)
  u16* o2  = (u16*)(ws + 69206016);           // 32768*512 bf16

  cast_both<<<1024, 256, 0, stream>>>(w_in, wq, w_out, wo);
  permute_in<<<dim3(256, 8), 256, 0, stream>>>(x, xw2);
  gemm_qkv_attn<<<2048, 256, 0, stream>>>(xw2, wq, b_in, o);
  gemm_out<<<512, 512, 0, stream>>>(o, wo, b_out, o2);
  permute_out<<<dim3(256, 8), 256, 0, stream>>>(o2, out);
}